// Round 12
// baseline (145.883 us; speedup 1.0000x reference)
//
#include <hip/hip_runtime.h>

#define B_    512
#define IN_   256
#define H_    512
#define OUT_  64
#define NDEATH (B_ - 1)
#define NSORT  512          // NDEATH padded to pow2 for bitonic sort / bsearch
#define RTOL_ 1e-6
#define ATOL_ 1e-8
#define NBLK  256
#define KT    64            // K-slab per LDS stage; wave-groups split it 2x32

typedef __attribute__((ext_vector_type(4))) double d4_t;

// agent-visible store: relaxed atomic, bypasses L2 -> lands at coherence
// point (L3). No dirty L2 lines => barriers need NO wbl2/inv fences. (R11)
__device__ __forceinline__ void ast(double* p, double v) {
    __hip_atomic_store(p, v, __ATOMIC_RELAXED, __HIP_MEMORY_SCOPE_AGENT);
}

// ---------------------------------------------------------------------------
// fenceless software grid barrier (R11-verified): __syncthreads drains vmcnt
// (all inter-phase data is ast -> already at L3); relaxed add + relaxed spin.
// ---------------------------------------------------------------------------
__device__ __forceinline__ void gbar(unsigned* cnt, unsigned nb) {
    __syncthreads();
    if (threadIdx.x == 0) {
        __hip_atomic_fetch_add(cnt, 1u, __ATOMIC_RELAXED,
                               __HIP_MEMORY_SCOPE_AGENT);
        while (__hip_atomic_load(cnt, __ATOMIC_RELAXED,
                                 __HIP_MEMORY_SCOPE_AGENT) < nb)
            __builtin_amdgcn_s_sleep(2);
    }
    __syncthreads();
}

// ---------------------------------------------------------------------------
// per-block: bitonic-sort deaths into LDS (512 thr, 1 elem/thread), emit
// sorted tolerance windows (lo/hi both strictly increasing in d).
// ---------------------------------------------------------------------------
__device__ void sort_windows(const float* __restrict__ deaths,
                             double* sd, double* slo, double* shi, int t) {
    sd[t] = (t < NDEATH) ? (double)deaths[t] : 1e300;
    __syncthreads();
    for (int k = 2; k <= NSORT; k <<= 1) {
        for (int j = k >> 1; j > 0; j >>= 1) {
            int ixj = t ^ j;
            if (ixj > t) {
                double a = sd[t], b = sd[ixj];
                bool up = ((t & k) == 0);
                if ((a > b) == up) { sd[t] = b; sd[ixj] = a; }
            }
            __syncthreads();
        }
    }
    double d = sd[t];
    double w = ATOL_ + RTOL_ * fabs(d);
    slo[t] = d - w;
    shi[t] = d + w;
    __syncthreads();
}

// ---------------------------------------------------------------------------
// f64 MFMA GEMM phase, R12: 512 threads (8 waves = 2/SIMD). One 32x32 tile
// per block; KT=64 LDS slab per stage; wave-group g (wave>>2) computes the
// k-half [g*32, g*32+32) -> 8 iters at K=512 and 2 waves/SIMD to overlap
// stalls. Same A/W panels as R11 => zero extra global traffic (unlike R9's
// global K-split). Halves combined via LDS: total = half0 + half1 (fixed
// order; f64 rounding delta ~1e-16 — empirically benign, R9).
// ---------------------------------------------------------------------------
template <typename TIN, bool RELU>
__device__ void gemm_dev(const TIN* __restrict__ A, const float* __restrict__ W,
                         const float* __restrict__ bias, double* __restrict__ C,
                         int N, int K, int bid, int t,
                         double (&As)[2][KT][33], double (&Ws)[2][KT][33]) {
    const int lane = t & 63;
    const int wave = t >> 6;          // 0..7
    const int wg   = wave >> 2;       // k-half 0/1
    const int wv   = wave & 3;
    const int wm   = wv & 1, wn = wv >> 1;
    const int nbx  = N >> 5;
    const int row0 = (bid / nbx) << 5;
    const int col0 = (bid % nbx) << 5;

    const int akk = t & 63;           // k within A slab
    const int amm = t >> 6;           // A rows amm+8p
    const int wnn = t & 31;           // W col
    const int wkk = t >> 5;           // W k-rows wkk+16p
    const int nkt = K >> 6;           // 512 -> 8, 256 -> 4

    TIN   ar[2][4];
    float wr[2][4];

    auto load_to = [&](int rs, int kt) {
        const int k0 = kt << 6;
        #pragma unroll
        for (int p = 0; p < 4; ++p) {
            ar[rs][p] = A[(size_t)(row0 + amm + 8 * p) * K + k0 + akk];
            wr[rs][p] = W[(size_t)(k0 + wkk + 16 * p) * N + col0 + wnn];
        }
    };
    auto stage = [&](int rs, int buf) {
        #pragma unroll
        for (int p = 0; p < 4; ++p) {
            As[buf][akk][amm + 8 * p]  = (double)ar[rs][p];
            Ws[buf][wkk + 16 * p][wnn] = (double)wr[rs][p];
        }
    };

    load_to(0, 0);
    if (nkt > 1) load_to(1, 1);
    stage(0, 0);
    __syncthreads();

    d4_t c4 = {0.0, 0.0, 0.0, 0.0};
    const int mrow  = wm * 16 + (lane & 15);
    const int ncol  = wn * 16 + (lane & 15);
    const int kq    = lane >> 4;
    const int kbase = wg * 32;

    for (int kt = 0; kt < nkt; ++kt) {
        const int cur = kt & 1;
        if (kt + 2 < nkt) load_to(cur, kt + 2);   // depth-2 prefetch
        #pragma unroll
        for (int ks = 0; ks < 8; ++ks) {
            double av = As[cur][kbase + ks * 4 + kq][mrow];
            double bv = Ws[cur][kbase + ks * 4 + kq][ncol];
            c4 = __builtin_amdgcn_mfma_f64_16x16x4f64(av, bv, c4, 0, 0, 0);
        }
        __syncthreads();                          // all reads of LDS done
        if (kt + 1 < nkt) stage(cur ^ 1, cur ^ 1);
        __syncthreads();                          // next buffer filled
    }

    // combine the two k-halves through LDS (As is free now)
    double* cs = &As[0][0][0];                    // 4*64*4 = 1024 doubles
    if (wg == 1) {
        #pragma unroll
        for (int r = 0; r < 4; ++r) cs[((wv * 64 + lane) << 2) + r] = c4[r];
    }
    __syncthreads();
    if (wg == 0) {
        #pragma unroll
        for (int r = 0; r < 4; ++r) {
            int row = row0 + wm * 16 + (lane >> 4) * 4 + r;
            int col = col0 + wn * 16 + (lane & 15);
            double v = c4[r] + cs[((wv * 64 + lane) << 2) + r];  // h0 + h1
            v += (double)bias[col];
            if (RELU) v = v > 0.0 ? v : 0.0;
            ast(&C[(size_t)row * N + col], v);
        }
    }
    __syncthreads();                              // cs reuse safety
}

// ---------------------------------------------------------------------------
// column c: mean + target-MSE partial + compactness partial (512 threads,
// one row each) -> global slots
// ---------------------------------------------------------------------------
__device__ void mc_dev(const float* __restrict__ target,
                       const double* __restrict__ y,
                       double* __restrict__ t_part, double* __restrict__ c_part,
                       int c, int t, double* red) {
    const int wave = t >> 6, lane = t & 63;
    double v = y[(size_t)t * OUT_ + c];
    double s = v;
    for (int off = 32; off; off >>= 1) s += __shfl_down(s, off);
    __shared__ double smean;
    if (lane == 0) red[wave] = s;
    __syncthreads();
    if (t == 0) {
        double m = 0.0;
        for (int w = 0; w < 8; ++w) m += red[w];
        smean = m / (double)B_;
    }
    __syncthreads();
    double m = smean;
    double d = (double)target[(size_t)t * OUT_ + c] - v;
    double t_s = d * d;
    double c_s = fabs(v - m);
    for (int off = 32; off; off >>= 1) {
        t_s += __shfl_down(t_s, off);
        c_s += __shfl_down(c_s, off);
    }
    if (lane == 0) { red[wave] = t_s; red[8 + wave] = c_s; }
    __syncthreads();
    if (t == 0) {
        double ts = 0.0, cs = 0.0;
        for (int w = 0; w < 8; ++w) { ts += red[w]; cs += red[8 + w]; }
        ast(&t_part[c], ts);
        ast(&c_part[c], cs);
    }
}

// ---------------------------------------------------------------------------
// pdist + sorted-window match, 512 threads. Block b: rows b and 510-b
// (512 pairs, exactly one per thread). Match: lo/hi increasing => pd in any
// window <=> hi[ub-1] >= pd, ub from 9-step bsearch.
// ---------------------------------------------------------------------------
__device__ __forceinline__ double pair_val(const double* __restrict__ yrow_s,
                                           const double* __restrict__ yj,
                                           const double* __restrict__ slo,
                                           const double* __restrict__ shi) {
    double s = 0.0;
    #pragma unroll
    for (int d = 0; d < OUT_; d += 2) {
        double2 v = *(const double2*)(yj + d);
        double d0 = yrow_s[d]     - v.x;
        double d1 = yrow_s[d + 1] - v.y;
        s = fma(d0, d0, s);
        s = fma(d1, d1, s);
    }
    double pd = sqrt(s);
    int pos = 0;
    #pragma unroll
    for (int step = NSORT / 2; step; step >>= 1) {
        if (slo[pos + step - 1] <= pd) pos += step;
    }
    bool m = (pos > 0) && (shi[pos - 1] >= pd);
    return m ? pd : 0.0;
}

__device__ void pdist_dev(const double* __restrict__ y,
                          double* __restrict__ hom_part, int bid, int t,
                          double* yA, double* yB,
                          const double* slo, const double* shi, double* red) {
    const int iA = bid;
    const int iB = 510 - bid;     // == iA when bid == 255
    if (t < OUT_)            yA[t]        = y[(size_t)iA * OUT_ + t];
    else if (t < 2 * OUT_)   yB[t - OUT_] = y[(size_t)iB * OUT_ + (t - OUT_)];
    __syncthreads();

    double local = 0.0;
    for (int j = iA + 1 + t; j < B_; j += 512)
        local += pair_val(yA, y + (size_t)j * OUT_, slo, shi);
    if (iB != iA)
        for (int j = iB + 1 + t; j < B_; j += 512)
            local += pair_val(yB, y + (size_t)j * OUT_, slo, shi);

    for (int off = 32; off; off >>= 1) local += __shfl_down(local, off);
    int wave = t >> 6, lane = t & 63;
    if (lane == 0) red[wave] = local;
    __syncthreads();
    if (t == 0) {
        double s = 0.0;
        for (int w = 0; w < 8; ++w) s += red[w];
        ast(&hom_part[bid], s);
    }
}

// ---------------------------------------------------------------------------
// the single fused persistent kernel: 256 blocks x 512 threads (2 blocks'
// worth of waves per CU without extra traffic). 4 barriers + last-block
// finalize (replaces barrier 5).
// ---------------------------------------------------------------------------
__global__ __launch_bounds__(512) void fused_k(
    const float* __restrict__ batch, const float* __restrict__ target,
    const float* __restrict__ W1, const float* __restrict__ b1,
    const float* __restrict__ W2, const float* __restrict__ b2,
    const float* __restrict__ W3, const float* __restrict__ b3,
    const float* __restrict__ Wout, const float* __restrict__ bout,
    const float* __restrict__ deaths, float* __restrict__ out,
    double* __restrict__ hA, double* __restrict__ hB,
    double* __restrict__ hC, double* __restrict__ yv,
    double* __restrict__ hom_part, double* __restrict__ t_part,
    double* __restrict__ c_part, unsigned* __restrict__ cnt) {
    const int bid = blockIdx.x;
    const int t   = threadIdx.x;

    __shared__ double As[2][KT][33];
    __shared__ double Ws[2][KT][33];
    __shared__ double slo[NSORT], shi[NSORT];
    __shared__ double yA[OUT_], yB[OUT_];
    __shared__ double red[16];
    __shared__ int    lastf;
    double* sd = &As[0][0][0];                // sort scratch alias (512 dbl)

    // P0..P2: the three 512x512 GEMMs on all 256 blocks (write-once chain)
    gemm_dev<float,  true>(batch, W1, b1, hA, H_, IN_, bid, t, As, Ws);
    gbar(&cnt[0], NBLK);
    gemm_dev<double, true>(hA, W2, b2, hB, H_, H_, bid, t, As, Ws);
    gbar(&cnt[1], NBLK);
    gemm_dev<double, true>(hB, W3, b3, hC, H_, H_, bid, t, As, Ws);
    gbar(&cnt[2], NBLK);

    // P3: Wout GEMM on blocks 0..31 (32 tiles, full K); others sort windows
    if (bid < 32) gemm_dev<double, false>(hC, Wout, bout, yv, OUT_, H_, bid, t, As, Ws);
    else          sort_windows(deaths, sd, slo, shi, t);
    gbar(&cnt[3], NBLK);
    if (bid < 32) sort_windows(deaths, sd, slo, shi, t);

    // P4: pdist on all 256 blocks; mean/MSE/compactness on blocks 0..63
    pdist_dev(yv, hom_part, bid, t, yA, yB, slo, shi, red);
    if (bid < OUT_) mc_dev(target, yv, t_part, c_part, bid, t, red);

    // P5: last block to arrive finalizes (no full barrier needed)
    __syncthreads();
    if (t == 0) {
        unsigned prev = __hip_atomic_fetch_add(&cnt[4], 1u, __ATOMIC_RELAXED,
                                               __HIP_MEMORY_SCOPE_AGENT);
        lastf = (prev == NBLK - 1);
    }
    __syncthreads();
    if (lastf) {
        double h  = (t < NBLK) ? __hip_atomic_load(&hom_part[t], __ATOMIC_RELAXED,
                                                   __HIP_MEMORY_SCOPE_AGENT) : 0.0;
        double tp = 0.0, cp = 0.0;
        if (t < OUT_) {
            tp = __hip_atomic_load(&t_part[t], __ATOMIC_RELAXED,
                                   __HIP_MEMORY_SCOPE_AGENT);
            cp = __hip_atomic_load(&c_part[t], __ATOMIC_RELAXED,
                                   __HIP_MEMORY_SCOPE_AGENT);
        }
        for (int off = 32; off; off >>= 1) {
            h  += __shfl_down(h,  off);
            tp += __shfl_down(tp, off);
            cp += __shfl_down(cp, off);
        }
        int wave = t >> 6, lane = t & 63;
        if (lane == 0) { red[wave] = h; red[8 + wave] = tp + cp * 0.0; }
        __shared__ double red2[16];
        if (lane == 0) { red2[wave] = tp; red2[8 + wave] = cp; }
        __syncthreads();
        if (t == 0) {
            double hs = 0.0, ts = 0.0, cs = 0.0;
            for (int w = 0; w < 8; ++w) {
                hs += red[w]; ts += red2[w]; cs += red2[8 + w];
            }
            out[0] = (float)(ts / (double)(B_ * OUT_) + hs + 0.01 * cs);
        }
    }
}

extern "C" void kernel_launch(void* const* d_in, const int* in_sizes, int n_in,
                              void* d_out, int out_size, void* d_ws, size_t ws_size,
                              hipStream_t stream) {
    const float* batch  = (const float*)d_in[0];
    const float* target = (const float*)d_in[1];
    const float* W1     = (const float*)d_in[2];
    const float* b1     = (const float*)d_in[3];
    const float* W2     = (const float*)d_in[4];
    const float* b2     = (const float*)d_in[5];
    const float* W3     = (const float*)d_in[6];
    const float* b3     = (const float*)d_in[7];
    const float* Wout   = (const float*)d_in[8];
    const float* bout   = (const float*)d_in[9];
    const float* deaths = (const float*)d_in[10];
    float* out = (float*)d_out;

    double* hA       = (double*)d_ws;              // 512*512
    double* hB       = hA + (size_t)B_ * H_;       // 512*512
    double* hC       = hB + (size_t)B_ * H_;       // 512*512
    double* yv       = hC + (size_t)B_ * H_;       // 512*64
    double* hom_part = yv + (size_t)B_ * OUT_;     // 256
    double* t_part   = hom_part + NBLK;            // 64
    double* c_part   = t_part + OUT_;              // 64
    unsigned* cnt    = (unsigned*)(c_part + OUT_); // 8 uints (5 used)

    hipMemsetAsync(cnt, 0, 8 * sizeof(unsigned), stream);

    fused_k<<<dim3(NBLK), dim3(512), 0, stream>>>(
        batch, target, W1, b1, W2, b2, W3, b3, Wout, bout, deaths, out,
        hA, hB, hC, yv, hom_part, t_part, c_part, cnt);
}

// Round 13
// 131.458 us; speedup vs baseline: 1.1097x; 1.1097x over previous
//
#include <hip/hip_runtime.h>

#define B_    512
#define IN_   256
#define H_    512
#define OUT_  64
#define NDEATH (B_ - 1)
#define NSORT  512          // NDEATH padded to pow2 for bitonic sort / bsearch
#define RTOL_ 1e-6
#define ATOL_ 1e-8
#define NBLK  256
#define KT    32            // K-tile -> 16 iters for K=512 (R10/R11-verified)

typedef __attribute__((ext_vector_type(4))) double d4_t;

// agent-visible store: relaxed atomic, bypasses L2 -> lands at L3 coherence
// point. No dirty L2 lines => barriers need NO wbl2/inv fences. (R11-verified)
__device__ __forceinline__ void ast(double* p, double v) {
    __hip_atomic_store(p, v, __ATOMIC_RELAXED, __HIP_MEMORY_SCOPE_AGENT);
}

// ---------------------------------------------------------------------------
// fenceless software barrier (R11-verified protocol). R13: used with nb=16
// for GROUP-LOCAL barriers (phases are row-strip-local: block (g,c) only
// reads rows written by its own 16-block group) and nb=256 once before pdist.
// ---------------------------------------------------------------------------
__device__ __forceinline__ void gbar(unsigned* cnt, unsigned nb) {
    __syncthreads();
    if (threadIdx.x == 0) {
        __hip_atomic_fetch_add(cnt, 1u, __ATOMIC_RELAXED,
                               __HIP_MEMORY_SCOPE_AGENT);
        while (__hip_atomic_load(cnt, __ATOMIC_RELAXED,
                                 __HIP_MEMORY_SCOPE_AGENT) < nb)
            __builtin_amdgcn_s_sleep(2);
    }
    __syncthreads();
}

// ---------------------------------------------------------------------------
// per-block: bitonic-sort deaths into LDS, emit sorted tolerance windows.
// 256 threads, 512 elements. (verified R5-R12)
// ---------------------------------------------------------------------------
__device__ void sort_windows(const float* __restrict__ deaths,
                             double* sd, double* slo, double* shi, int t) {
    int i1 = t + 256;
    sd[t]  = (t  < NDEATH) ? (double)deaths[t]  : 1e300;
    sd[i1] = (i1 < NDEATH) ? (double)deaths[i1] : 1e300;
    __syncthreads();
    for (int k = 2; k <= NSORT; k <<= 1) {
        for (int j = k >> 1; j > 0; j >>= 1) {
            int l = ((t & ~(j - 1)) << 1) | (t & (j - 1));   // pair (l, l+j)
            int p = l + j;
            bool up = ((l & k) == 0);
            double a = sd[l], b = sd[p];
            if ((a > b) == up) { sd[l] = b; sd[p] = a; }
            __syncthreads();
        }
    }
    for (int i = t; i < NSORT; i += 256) {
        double d = sd[i];
        double w = ATOL_ + RTOL_ * fabs(d);
        slo[i] = d - w;
        shi[i] = d + w;
    }
    __syncthreads();
}

// ---------------------------------------------------------------------------
// f64 MFMA GEMM phase (R10/R11-verified, bit-identical): Kt=32, depth-2
// register prefetch, 256 thr / 4 waves, one 32x32 tile. C via ast.
// ---------------------------------------------------------------------------
template <typename TIN, bool RELU>
__device__ void gemm_dev(const TIN* __restrict__ A, const float* __restrict__ W,
                         const float* __restrict__ bias, double* __restrict__ C,
                         int N, int K, int tile, int t,
                         double (&As)[2][KT][33], double (&Ws)[2][KT][33]) {
    const int lane = t & 63;
    const int wave = t >> 6;
    const int wm   = wave & 1, wn = wave >> 1;
    const int nbx  = N >> 5;
    const int row0 = (tile / nbx) << 5;
    const int col0 = (tile % nbx) << 5;

    const int akk = t & 31;          // k within A tile
    const int amm = t >> 5;          // base row (rows amm+8p, p=0..3)
    const int wnn = t & 31;          // col within W tile
    const int wkk = t >> 5;          // base k (k-rows wkk+8p)
    const int nkt = K >> 5;

    TIN   ar[2][4];
    float wr[2][4];

    auto load_to = [&](int rs, int kt) {
        const int k0 = kt << 5;
        #pragma unroll
        for (int p = 0; p < 4; ++p) {
            ar[rs][p] = A[(size_t)(row0 + amm + 8 * p) * K + k0 + akk];
            wr[rs][p] = W[(size_t)(k0 + wkk + 8 * p) * N + col0 + wnn];
        }
    };
    auto stage = [&](int rs, int buf) {
        #pragma unroll
        for (int p = 0; p < 4; ++p) {
            As[buf][akk][amm + 8 * p] = (double)ar[rs][p];
            Ws[buf][wkk + 8 * p][wnn] = (double)wr[rs][p];
        }
    };

    load_to(0, 0);
    if (nkt > 1) load_to(1, 1);
    stage(0, 0);
    __syncthreads();

    d4_t c4 = {0.0, 0.0, 0.0, 0.0};
    const int mrow = wm * 16 + (lane & 15);
    const int ncol = wn * 16 + (lane & 15);
    const int kq   = lane >> 4;

    for (int kt = 0; kt < nkt; ++kt) {
        const int cur = kt & 1;
        if (kt + 2 < nkt) load_to(cur, kt + 2);   // depth-2 prefetch
        #pragma unroll
        for (int ks = 0; ks < KT / 4; ++ks) {
            double av = As[cur][ks * 4 + kq][mrow];
            double bv = Ws[cur][ks * 4 + kq][ncol];
            c4 = __builtin_amdgcn_mfma_f64_16x16x4f64(av, bv, c4, 0, 0, 0);
        }
        __syncthreads();                          // all reads of LDS done
        if (kt + 1 < nkt) stage(cur ^ 1, cur ^ 1);
        __syncthreads();                          // next buffer filled
    }

    #pragma unroll
    for (int r = 0; r < 4; ++r) {
        int row = row0 + wm * 16 + (lane >> 4) * 4 + r;
        int col = col0 + wn * 16 + (lane & 15);
        double v = c4[r] + (double)bias[col];
        if (RELU) v = v > 0.0 ? v : 0.0;
        ast(&C[(size_t)row * N + col], v);
    }
}

// ---------------------------------------------------------------------------
// column c: mean + target-MSE partial + compactness partial -> global slots
// ---------------------------------------------------------------------------
__device__ void mc_dev(const float* __restrict__ target,
                       const double* __restrict__ y,
                       double* __restrict__ t_part, double* __restrict__ c_part,
                       int c, int t) {
    const int wave = t >> 6, lane = t & 63;
    double v0 = y[(size_t)t * OUT_ + c];
    double v1 = y[(size_t)(t + 256) * OUT_ + c];
    double s = v0 + v1;
    for (int off = 32; off; off >>= 1) s += __shfl_down(s, off);
    __shared__ double swm[4];
    __shared__ double smean;
    if (lane == 0) swm[wave] = s;
    __syncthreads();
    if (t == 0) smean = (swm[0] + swm[1] + swm[2] + swm[3]) / (double)B_;
    __syncthreads();
    double m = smean;
    double d0 = (double)target[(size_t)t * OUT_ + c] - v0;
    double d1 = (double)target[(size_t)(t + 256) * OUT_ + c] - v1;
    double t_s = d0 * d0 + d1 * d1;
    double c_s = fabs(v0 - m) + fabs(v1 - m);
    for (int off = 32; off; off >>= 1) {
        t_s += __shfl_down(t_s, off);
        c_s += __shfl_down(c_s, off);
    }
    __shared__ double st[4], sc[4];
    if (lane == 0) { st[wave] = t_s; sc[wave] = c_s; }
    __syncthreads();
    if (t == 0) {
        ast(&t_part[c], st[0] + st[1] + st[2] + st[3]);
        ast(&c_part[c], sc[0] + sc[1] + sc[2] + sc[3]);
    }
}

// ---------------------------------------------------------------------------
// pdist + sorted-window match. Block b: rows b and 510-b (512 pairs each,
// balanced). Match: lo/hi increasing => pd in any window <=> hi[ub-1] >= pd.
// ---------------------------------------------------------------------------
__device__ __forceinline__ double pair_val(const double* __restrict__ yrow_s,
                                           const double* __restrict__ yj,
                                           const double* __restrict__ slo,
                                           const double* __restrict__ shi) {
    double s = 0.0;
    #pragma unroll
    for (int d = 0; d < OUT_; d += 2) {
        double2 v = *(const double2*)(yj + d);
        double d0 = yrow_s[d]     - v.x;
        double d1 = yrow_s[d + 1] - v.y;
        s = fma(d0, d0, s);
        s = fma(d1, d1, s);
    }
    double pd = sqrt(s);
    int pos = 0;
    #pragma unroll
    for (int step = NSORT / 2; step; step >>= 1) {
        if (slo[pos + step - 1] <= pd) pos += step;
    }
    bool m = (pos > 0) && (shi[pos - 1] >= pd);
    return m ? pd : 0.0;
}

__device__ void pdist_dev(const double* __restrict__ y,
                          double* __restrict__ hom_part, int bid, int t,
                          double* yA, double* yB,
                          const double* slo, const double* shi) {
    const int iA = bid;
    const int iB = 510 - bid;     // == iA when bid == 255
    if (t < OUT_)            yA[t]        = y[(size_t)iA * OUT_ + t];
    else if (t < 2 * OUT_)   yB[t - OUT_] = y[(size_t)iB * OUT_ + (t - OUT_)];
    __syncthreads();

    double local = 0.0;
    for (int j = iA + 1 + t; j < B_; j += 256)
        local += pair_val(yA, y + (size_t)j * OUT_, slo, shi);
    if (iB != iA)
        for (int j = iB + 1 + t; j < B_; j += 256)
            local += pair_val(yB, y + (size_t)j * OUT_, slo, shi);

    for (int off = 32; off; off >>= 1) local += __shfl_down(local, off);
    __shared__ double sw[4];
    int wave = t >> 6, lane = t & 63;
    if (lane == 0) sw[wave] = local;
    __syncthreads();
    if (t == 0) ast(&hom_part[bid], sw[0] + sw[1] + sw[2] + sw[3]);
}

// ---------------------------------------------------------------------------
// single fused persistent kernel, R13: 16 groups of 16 blocks. Group g owns
// row-strip g (rows 32g..32g+31) through the whole MLP; phases P0..P2 sync
// with GROUP-LOCAL 16-arrival barriers (cacheline-padded counters -> no
// global convoy, 16 independent pipelines). One global barrier before pdist.
// Counter layout (uints): grp g phase p -> cnt[g*32+p]; global -> cnt[512];
// finalize -> cnt[544].
// ---------------------------------------------------------------------------
__global__ __launch_bounds__(256) void fused_k(
    const float* __restrict__ batch, const float* __restrict__ target,
    const float* __restrict__ W1, const float* __restrict__ b1,
    const float* __restrict__ W2, const float* __restrict__ b2,
    const float* __restrict__ W3, const float* __restrict__ b3,
    const float* __restrict__ Wout, const float* __restrict__ bout,
    const float* __restrict__ deaths, float* __restrict__ out,
    double* __restrict__ hA, double* __restrict__ hB,
    double* __restrict__ hC, double* __restrict__ yv,
    double* __restrict__ hom_part, double* __restrict__ t_part,
    double* __restrict__ c_part, unsigned* __restrict__ cnt) {
    const int bid = blockIdx.x;
    const int t   = threadIdx.x;
    const int g   = bid >> 4;     // group = row-strip
    const int c   = bid & 15;     // col-tile within group
    unsigned* gc  = cnt + g * 32; // group-private counter line

    __shared__ double As[2][KT][33];
    __shared__ double Ws[2][KT][33];
    __shared__ double slo[NSORT], shi[NSORT];
    __shared__ double yA[OUT_], yB[OUT_];
    __shared__ int    lastf;
    double* sd = &As[0][0][0];                // sort scratch alias (512 dbl)

    // P0..P2: three 512x512 GEMMs; tile = g*16+c = bid (row0=32g, col0=32c).
    // Group-local barriers: block (g,c) reads only rows 32g..32g+31 of the
    // previous buffer, written exclusively by blocks (g, 0..15).
    gemm_dev<float,  true>(batch, W1, b1, hA, H_, IN_, bid, t, As, Ws);
    gbar(&gc[0], 16);
    gemm_dev<double, true>(hA, W2, b2, hB, H_, H_, bid, t, As, Ws);
    gbar(&gc[1], 16);
    gemm_dev<double, true>(hB, W3, b3, hC, H_, H_, bid, t, As, Ws);
    gbar(&gc[2], 16);

    // P3: Wout tile g*2+c on c<2 (row-strip g -> group-local dep); c>=2 sort
    if (c < 2) gemm_dev<double, false>(hC, Wout, bout, yv, OUT_, H_, g * 2 + c, t, As, Ws);
    else       sort_windows(deaths, sd, slo, shi, t);

    // single global barrier: pdist needs all of yv
    gbar(&cnt[512], NBLK);
    if (c < 2) sort_windows(deaths, sd, slo, shi, t);

    // P4: pdist on all 256 blocks; mean/MSE/compactness on blocks 0..63
    pdist_dev(yv, hom_part, bid, t, yA, yB, slo, shi);
    if (bid < OUT_) mc_dev(target, yv, t_part, c_part, bid, t);

    // P5: last block to arrive finalizes
    __syncthreads();
    if (t == 0) {
        unsigned prev = __hip_atomic_fetch_add(&cnt[544], 1u, __ATOMIC_RELAXED,
                                               __HIP_MEMORY_SCOPE_AGENT);
        lastf = (prev == NBLK - 1);
    }
    __syncthreads();
    if (lastf) {
        double h  = __hip_atomic_load(&hom_part[t], __ATOMIC_RELAXED,
                                      __HIP_MEMORY_SCOPE_AGENT);
        double tp = 0.0, cp = 0.0;
        if (t < OUT_) {
            tp = __hip_atomic_load(&t_part[t], __ATOMIC_RELAXED,
                                   __HIP_MEMORY_SCOPE_AGENT);
            cp = __hip_atomic_load(&c_part[t], __ATOMIC_RELAXED,
                                   __HIP_MEMORY_SCOPE_AGENT);
        }
        for (int off = 32; off; off >>= 1) {
            h  += __shfl_down(h,  off);
            tp += __shfl_down(tp, off);
            cp += __shfl_down(cp, off);
        }
        __shared__ double sh[4], stp[4], scp[4];
        int wave = t >> 6, lane = t & 63;
        if (lane == 0) { sh[wave] = h; stp[wave] = tp; scp[wave] = cp; }
        __syncthreads();
        if (t == 0) {
            double hs = sh[0]  + sh[1]  + sh[2]  + sh[3];
            double ts = stp[0] + stp[1] + stp[2] + stp[3];
            double cs = scp[0] + scp[1] + scp[2] + scp[3];
            out[0] = (float)(ts / (double)(B_ * OUT_) + hs + 0.01 * cs);
        }
    }
}

extern "C" void kernel_launch(void* const* d_in, const int* in_sizes, int n_in,
                              void* d_out, int out_size, void* d_ws, size_t ws_size,
                              hipStream_t stream) {
    const float* batch  = (const float*)d_in[0];
    const float* target = (const float*)d_in[1];
    const float* W1     = (const float*)d_in[2];
    const float* b1     = (const float*)d_in[3];
    const float* W2     = (const float*)d_in[4];
    const float* b2     = (const float*)d_in[5];
    const float* W3     = (const float*)d_in[6];
    const float* b3     = (const float*)d_in[7];
    const float* Wout   = (const float*)d_in[8];
    const float* bout   = (const float*)d_in[9];
    const float* deaths = (const float*)d_in[10];
    float* out = (float*)d_out;

    double* hA       = (double*)d_ws;              // 512*512
    double* hB       = hA + (size_t)B_ * H_;       // 512*512
    double* hC       = hB + (size_t)B_ * H_;       // 512*512
    double* yv       = hC + (size_t)B_ * H_;       // 512*64
    double* hom_part = yv + (size_t)B_ * OUT_;     // 256
    double* t_part   = hom_part + NBLK;            // 64
    double* c_part   = t_part + OUT_;              // 64
    unsigned* cnt    = (unsigned*)(c_part + OUT_); // 576 uints

    hipMemsetAsync(cnt, 0, 576 * sizeof(unsigned), stream);

    fused_k<<<dim3(NBLK), dim3(256), 0, stream>>>(
        batch, target, W1, b1, W2, b2, W3, b3, Wout, bout, deaths, out,
        hA, hB, hC, yv, hom_part, t_part, c_part, cnt);
}